// Round 1
// baseline (1071.011 us; speedup 1.0000x reference)
//
#include <hip/hip_runtime.h>
#include <hip/hip_bf16.h>
#include <math.h>

typedef __bf16 bf16x8 __attribute__((ext_vector_type(8)));
typedef short  s16x8  __attribute__((ext_vector_type(8)));
typedef float  f32x4  __attribute__((ext_vector_type(4)));
typedef unsigned short u16;

// ---- sizes ----
#define NN 32
#define CC 256
#define HH 56
#define WW 56
#define HP 68            // padded spatial (6 halo each side)
#define XP2_BYTES 75759616ull            // 32*68*68*256*2
#define WT2_BYTES 3276800ull             // 25*8*4*256*8*2
#define T1_BYTES  1835008ull             // 32*256*56*4
#define XP2_OFF 0ull
#define WT2_OFF 75759616ull
#define T1_OFF  79036416ull
#define T9_OFF  80871424ull

__device__ inline u16 f2bf(float f) {
    unsigned int u = __builtin_bit_cast(unsigned int, f);
    u = (u + 0x7fffu + ((u >> 16) & 1u)) >> 16;   // RNE
    return (u16)u;
}

// ---- zero xp2 (halo must be 0; ws is poisoned 0xAA each call) ----
__global__ void zero_xp2(u16* __restrict__ xp2, size_t n16) {
    size_t i = (size_t)blockIdx.x * blockDim.x + threadIdx.x;
    size_t stride = (size_t)gridDim.x * blockDim.x;
    uint4* p = (uint4*)xp2;
    uint4 z; z.x = z.y = z.z = z.w = 0u;
    for (; i < n16; i += stride) p[i] = z;
}

// ---- pack x -> xp2[n][h+6][w+6][c] bf16, c innermost ----
__global__ __launch_bounds__(64)
void pack_x(const float* __restrict__ x, u16* __restrict__ xp2) {
    int b = blockIdx.x;
    int oct = b & 31;            // c-octet: c0 = oct*8
    int h = (b >> 5) % HH;
    int n = b / (32 * HH);
    int w = threadIdx.x;
    if (w >= WW) return;
    const float* src = x + (((size_t)(n * CC + oct * 8)) * HH + h) * WW + w;
    s16x8 pk;
#pragma unroll
    for (int j = 0; j < 8; ++j) pk[j] = (short)f2bf(src[(size_t)j * (HH * WW)]);
    *(s16x8*)(xp2 + (((size_t)n * HP + (h + 6)) * HP + (w + 6)) * CC + oct * 8) = pk;
}

// ---- pack w7 -> wt2[tap][chunk][q][c_out][j] bf16 (A-fragment order) ----
__global__ __launch_bounds__(256)
void pack_w(const float* __restrict__ w7, u16* __restrict__ wt2) {
    int idx = blockIdx.x * 256 + threadIdx.x;    // 256*6400 total
    int c_out = idx / 6400;
    int k = idx - c_out * 6400;
    int cin = k / 25;
    int tap = k - cin * 25;
    int chunk = cin >> 5;
    int qq = (cin >> 3) & 3;
    int j = cin & 7;
    wt2[((((size_t)tap * 8 + chunk) * 4 + qq) * CC + c_out) * 8 + j] = f2bf(w7[idx]);
}

// ---- t1 (row max) + t9 (softmax over w of einsum) ----
__global__ __launch_bounds__(256)
void t169_kernel(const float* __restrict__ x, const float* __restrict__ w6,
                 float* __restrict__ t1, float* __restrict__ t9) {
    const int n = blockIdx.x / HH;
    const int h = blockIdx.x % HH;
    const int wave = threadIdx.x >> 6;
    const int lane = threadIdx.x & 63;
    const bool valid = lane < WW;
    const int wl = valid ? lane : (WW - 1);
    const float* xrow = x + ((size_t)(n * CC) * HH + h) * WW;
    float accw = 0.f;
    __shared__ float sbuf[4 * 64];
    for (int i = 0; i < 64; ++i) {
        int c = wave * 64 + i;
        float xv = xrow[(size_t)c * (HH * WW) + wl];
        float xm = valid ? xv : -INFINITY;
#pragma unroll
        for (int off = 32; off > 0; off >>= 1)
            xm = fmaxf(xm, __shfl_xor(xm, off));
        if (lane == 0) t1[(size_t)(n * CC + c) * HH + h] = xm;
        if (valid) accw += tanhf(fmaxf(xv, 0.f)) * w6[c];
    }
    sbuf[wave * 64 + lane] = accw;
    __syncthreads();
    if (wave == 0) {
        float s = sbuf[lane] + sbuf[64 + lane] + sbuf[128 + lane] + sbuf[192 + lane];
        float sm = valid ? s : -INFINITY;
        float mx = sm;
#pragma unroll
        for (int off = 32; off > 0; off >>= 1)
            mx = fmaxf(mx, __shfl_xor(mx, off));
        float e = valid ? expf(s - mx) : 0.f;
        float tot = e;
#pragma unroll
        for (int off = 32; off > 0; off >>= 1)
            tot += __shfl_xor(tot, off);
        if (valid) t9[((size_t)n * HH + h) * WW + lane] = e / tot;
    }
}

// ---- main: dilated conv as implicit GEMM (bf16 MFMA) + fused epilogue ----
// block = 256 thr = 4 waves; wave w -> c_out [w*64, w*64+64); spatial = 2 rows (112 pos)
__global__ __launch_bounds__(256, 2)
void conv_main(const u16* __restrict__ xp2, const u16* __restrict__ wt2,
               const float* __restrict__ x, const float* __restrict__ t1,
               const float* __restrict__ t9, float* __restrict__ out) {
    const int blk = blockIdx.x;
    const int n = blk / 28;
    const int h0 = (blk % 28) * 2;
    const int wave = threadIdx.x >> 6;
    const int lane = threadIdx.x & 63;
    const int q = lane >> 4;
    const int m = lane & 15;
    const int cbase = wave * 64;

    int lrA[7], wpA[7];
#pragma unroll
    for (int st = 0; st < 7; ++st) {
        int p = st * 16 + m;
        int l = (p >= WW) ? 1 : 0;
        lrA[st] = l;
        wpA[st] = p - WW * l;
    }

    f32x4 acc[4][7];
#pragma unroll
    for (int ct = 0; ct < 4; ++ct)
#pragma unroll
        for (int st = 0; st < 7; ++st) {
            acc[ct][st][0] = 0.f; acc[ct][st][1] = 0.f;
            acc[ct][st][2] = 0.f; acc[ct][st][3] = 0.f;
        }

    const size_t nbase = (size_t)n * (HP * HP * CC);

    for (int tap = 0; tap < 25; ++tap) {
        const int dh = (tap / 5) * 3 - 6;
        const int dw = (tap % 5) * 3 - 6;
        const u16* xr0 = xp2 + nbase + ((size_t)(h0 + dh + 6) * HP + (dw + 6)) * CC + q * 8;
        const u16* xr1 = xr0 + HP * CC;
        const u16* wb = wt2 + (size_t)tap * (8 * 4 * CC * 8) + q * (CC * 8) + (cbase + m) * 8;
#pragma unroll
        for (int chunk = 0; chunk < 8; ++chunk) {
            const u16* wc = wb + chunk * (4 * CC * 8);
            bf16x8 a[4];
#pragma unroll
            for (int ct = 0; ct < 4; ++ct)
                a[ct] = *(const bf16x8*)(const void*)(wc + ct * (16 * 8));
            bf16x8 b[7];
            const int ko = chunk * 32;
#pragma unroll
            for (int st = 0; st < 7; ++st) {
                const u16* bp = (lrA[st] ? xr1 : xr0) + wpA[st] * CC + ko;
                b[st] = *(const bf16x8*)(const void*)bp;
            }
#pragma unroll
            for (int ct = 0; ct < 4; ++ct)
#pragma unroll
                for (int st = 0; st < 7; ++st)
                    acc[ct][st] = __builtin_amdgcn_mfma_f32_16x16x32_bf16(
                        a[ct], b[st], acc[ct][st], 0, 0, 0);
        }
    }

    // epilogue: out = t1 - (t9 * roll(x,2,h) + x * t7)
#pragma unroll
    for (int st = 0; st < 7; ++st) {
        const int l = lrA[st];
        const int w = wpA[st];
        const int h = h0 + l;
        const float t9v = t9[((size_t)n * HH + h) * WW + w];
        const int hprev = (h >= 2) ? (h - 2) : (h + HH - 2);
#pragma unroll
        for (int ct = 0; ct < 4; ++ct) {
            const int c0 = cbase + ct * 16 + q * 4;
#pragma unroll
            for (int r = 0; r < 4; ++r) {
                const int c = c0 + r;
                const size_t rowi = (size_t)(n * CC + c) * HH;
                const float t1v = t1[rowi + h];
                const float xv = x[(rowi + h) * WW + w];
                const float xr = x[(rowi + hprev) * WW + w];
                out[(rowi + h) * WW + w] = t1v - (t9v * xr + xv * acc[ct][st][r]);
            }
        }
    }
}

extern "C" void kernel_launch(void* const* d_in, const int* in_sizes, int n_in,
                              void* d_out, int out_size, void* d_ws, size_t ws_size,
                              hipStream_t stream) {
    const float* x  = (const float*)d_in[0];
    const float* w6 = (const float*)d_in[1];
    const float* w7 = (const float*)d_in[2];
    float* out = (float*)d_out;
    char* ws = (char*)d_ws;
    u16*   xp2 = (u16*)(ws + XP2_OFF);
    u16*   wt2 = (u16*)(ws + WT2_OFF);
    float* t1  = (float*)(ws + T1_OFF);
    float* t9  = (float*)(ws + T9_OFF);

    zero_xp2<<<dim3(2048), dim3(256), 0, stream>>>(xp2, XP2_BYTES / 16);
    pack_x<<<dim3(NN * HH * 32), dim3(64), 0, stream>>>(x, xp2);
    pack_w<<<dim3(6400), dim3(256), 0, stream>>>(w7, wt2);
    t169_kernel<<<dim3(NN * HH), dim3(256), 0, stream>>>(x, w6, t1, t9);
    conv_main<<<dim3(NN * 28), dim3(256), 0, stream>>>(xp2, wt2, x, t1, t9, out);
}

// Round 2
// 723.258 us; speedup vs baseline: 1.4808x; 1.4808x over previous
//
#include <hip/hip_runtime.h>
#include <hip/hip_bf16.h>
#include <math.h>

typedef __bf16 bf16x8 __attribute__((ext_vector_type(8)));
typedef short  s16x8  __attribute__((ext_vector_type(8)));
typedef float  f32x4  __attribute__((ext_vector_type(4)));
typedef unsigned short u16;

// ---- sizes ----
#define NN 32
#define CC 256
#define HH 56
#define WW 56
#define HP 68            // padded spatial (6 halo each side)
#define XP2_BYTES 75759616ull            // 32*68*68*256*2
#define XP2_OFF 0ull
#define WT3_OFF 75759616ull              // 25*8*256*32*2 = 3276800
#define T1_OFF  79036416ull              // 32*256*56*4 = 1835008
#define T9_OFF  80871424ull              // 32*56*56*4

__device__ inline u16 f2bf(float f) {
    unsigned int u = __builtin_bit_cast(unsigned int, f);
    u = (u + 0x7fffu + ((u >> 16) & 1u)) >> 16;   // RNE
    return (u16)u;
}

__device__ inline void gl_lds16(const char* g, char* l) {
    __builtin_amdgcn_global_load_lds(
        (const __attribute__((address_space(1))) unsigned int*)g,
        (__attribute__((address_space(3))) unsigned int*)l, 16, 0, 0);
}

// ---- zero xp2 (halo must be 0; ws is poisoned 0xAA each call) ----
__global__ void zero_xp2(u16* __restrict__ xp2, size_t n16) {
    size_t i = (size_t)blockIdx.x * blockDim.x + threadIdx.x;
    size_t stride = (size_t)gridDim.x * blockDim.x;
    uint4* p = (uint4*)xp2;
    uint4 z; z.x = z.y = z.z = z.w = 0u;
    for (; i < n16; i += stride) p[i] = z;
}

// ---- pack x -> xp2[n][h+6][w+6][c] bf16, c innermost ----
__global__ __launch_bounds__(256)
void pack_x(const float* __restrict__ x, u16* __restrict__ xp2) {
    int nh = blockIdx.x;
    int n = nh / HH, h = nh % HH;
    int lane = threadIdx.x & 63, wv = threadIdx.x >> 6;
    if (lane >= WW) return;
    const float* src = x + (size_t)n * (CC * HH * WW) + h * WW + lane;
    u16* dst = xp2 + (((size_t)n * HP + (h + 6)) * HP + (lane + 6)) * CC;
    for (int oct = wv; oct < 32; oct += 4) {
        s16x8 pk;
#pragma unroll
        for (int j = 0; j < 8; ++j)
            pk[j] = (short)f2bf(src[(size_t)(oct * 8 + j) * (HH * WW)]);
        *(s16x8*)(dst + oct * 8) = pk;
    }
}

// ---- pack w7 -> wt3[tap*8+chunk][c_out][32 cin] bf16 ----
__global__ __launch_bounds__(256)
void pack_w(const float* __restrict__ w7, u16* __restrict__ wt3) {
    int idx = blockIdx.x * 256 + threadIdx.x;    // 256*6400 total
    int c_out = idx / 6400;
    int k = idx - c_out * 6400;
    int cin = k / 25;
    int tap = k - cin * 25;
    int chunk = cin >> 5;
    int ci = cin & 31;
    wt3[(((size_t)(tap * 8 + chunk)) * CC + c_out) * 32 + ci] = f2bf(w7[idx]);
}

// ---- t1 (row max) + t9 (softmax over w of einsum) ----
__global__ __launch_bounds__(256)
void t169_kernel(const float* __restrict__ x, const float* __restrict__ w6,
                 float* __restrict__ t1, float* __restrict__ t9) {
    const int n = blockIdx.x / HH;
    const int h = blockIdx.x % HH;
    const int wave = threadIdx.x >> 6;
    const int lane = threadIdx.x & 63;
    const bool valid = lane < WW;
    const int wl = valid ? lane : (WW - 1);
    const float* xrow = x + ((size_t)(n * CC) * HH + h) * WW;
    float accw = 0.f;
    __shared__ float sbuf[4 * 64];
    for (int i = 0; i < 64; ++i) {
        int c = wave * 64 + i;
        float xv = xrow[(size_t)c * (HH * WW) + wl];
        float xm = valid ? xv : -INFINITY;
#pragma unroll
        for (int off = 32; off > 0; off >>= 1)
            xm = fmaxf(xm, __shfl_xor(xm, off));
        if (lane == 0) t1[(size_t)(n * CC + c) * HH + h] = xm;
        if (valid) accw += tanhf(fmaxf(xv, 0.f)) * w6[c];
    }
    sbuf[wave * 64 + lane] = accw;
    __syncthreads();
    if (wave == 0) {
        float s = sbuf[lane] + sbuf[64 + lane] + sbuf[128 + lane] + sbuf[192 + lane];
        float sm = valid ? s : -INFINITY;
        float mx = sm;
#pragma unroll
        for (int off = 32; off > 0; off >>= 1)
            mx = fmaxf(mx, __shfl_xor(mx, off));
        float e = valid ? expf(s - mx) : 0.f;
        float tot = e;
#pragma unroll
        for (int off = 32; off > 0; off >>= 1)
            tot += __shfl_xor(tot, off);
        if (valid) t9[((size_t)n * HH + h) * WW + lane] = e / tot;
    }
}

// ---- main: implicit GEMM, M=128 cout x N=128 flat-spatial, BK=32 ----
// 256 thr = 4 waves (2 cout-groups x 2 pos-groups), wave tile 64x64,
// double-buffered LDS staged via global_load_lds (waves 0-1: A, 2-3: B)
__global__ __launch_bounds__(256, 3)
void conv_main(const char* __restrict__ xp2b, const char* __restrict__ wt3b,
               const float* __restrict__ x, const float* __restrict__ t1,
               const float* __restrict__ t9, float* __restrict__ out) {
    const int blk = blockIdx.x;
    const int g = blk & 1;            // cout group: couts [g*128, g*128+128)
    const int tile = blk >> 1;        // flat spatial tile: positions [tile*128, +128)
    const int tid = threadIdx.x;
    const int wid = tid >> 6;
    const int lane = tid & 63;
    const int m = lane & 15;
    const int q = lane >> 4;
    const int wgc = wid & 1;          // cout sub-group within block (64)
    const int wgp = wid >> 1;         // pos sub-group within block (64)

    __shared__ __align__(16) char smem[2][16384];  // per buf: A 8KB + B 8KB

    // staging source addresses (per thread, loop-invariant parts)
    const size_t aGoff = (size_t)g * 8192 + (size_t)wid * 4096 + (size_t)lane * 16;
    unsigned vb[4] = {0, 0, 0, 0};
    if (wid >= 2) {
#pragma unroll
        for (int i = 0; i < 4; ++i) {
            int p = tile * 128 + ((wid - 2) * 4 + i) * 16 + (lane >> 2);
            int n = p / (HH * WW);
            int rem = p - n * (HH * WW);
            int hh = rem / WW;
            int ww = rem - hh * WW;
            vb[i] = ((((unsigned)n * HP + hh + 6) * HP) + ww + 6) * 512 + (lane & 3) * 16;
        }
    }

    auto stage = [&](int kn, int nb) {
        char* dst = smem[nb];
        if (wid < 2) {
            const char* gsrc = wt3b + (size_t)kn * 16384 + aGoff;
            char* d = dst + wid * 4096 + lane * 16;
#pragma unroll
            for (int i = 0; i < 4; ++i) gl_lds16(gsrc + i * 1024, d + i * 1024);
        } else {
            const int tp = kn >> 3, ch = kn & 7;
            const ptrdiff_t tapoff =
                (ptrdiff_t)((tp / 5) * 3 - 6) * (HP * 512) +
                (ptrdiff_t)((tp % 5) * 3 - 6) * 512 + ch * 64;
            const char* gb = xp2b + tapoff;
            char* d = dst + 8192 + (wid - 2) * 4096 + lane * 16;
#pragma unroll
            for (int i = 0; i < 4; ++i) gl_lds16(gb + vb[i], d + i * 1024);
        }
    };

    f32x4 acc[4][4];
#pragma unroll
    for (int ct = 0; ct < 4; ++ct)
#pragma unroll
        for (int st = 0; st < 4; ++st) {
            acc[ct][st][0] = 0.f; acc[ct][st][1] = 0.f;
            acc[ct][st][2] = 0.f; acc[ct][st][3] = 0.f;
        }

    // frag read offsets within a buffer
    const int aOff = (wgc * 64 + m) * 64 + q * 16;          // + ct*1024
    const int bOff = 8192 + (wgp * 64 + m) * 64 + q * 16;   // + st*1024

    stage(0, 0);
    for (int k = 0; k < 200; ++k) {
        __syncthreads();           // drains vmcnt: buf[k&1] staged; prev compute done
        if (k < 199) stage(k + 1, (k + 1) & 1);
        const char* bp = smem[k & 1];
        bf16x8 av[4], bv[4];
#pragma unroll
        for (int ct = 0; ct < 4; ++ct)
            av[ct] = *(const bf16x8*)(const void*)(bp + aOff + ct * 1024);
#pragma unroll
        for (int st = 0; st < 4; ++st)
            bv[st] = *(const bf16x8*)(const void*)(bp + bOff + st * 1024);
#pragma unroll
        for (int ct = 0; ct < 4; ++ct)
#pragma unroll
            for (int st = 0; st < 4; ++st)
                acc[ct][st] = __builtin_amdgcn_mfma_f32_16x16x32_bf16(
                    av[ct], bv[st], acc[ct][st], 0, 0, 0);
    }

    // epilogue: out = t1 - (t9 * roll(x,2,h) + x * t7)
#pragma unroll
    for (int st = 0; st < 4; ++st) {
        const int p = tile * 128 + wgp * 64 + st * 16 + m;
        const int n = p / (HH * WW);
        const int rem = p - n * (HH * WW);
        const int h = rem / WW;
        const int w = rem - h * WW;
        const float t9v = t9[((size_t)n * HH + h) * WW + w];
        const int hprev = (h >= 2) ? (h - 2) : (h + HH - 2);
#pragma unroll
        for (int ct = 0; ct < 4; ++ct) {
            const int c = g * 128 + wgc * 64 + ct * 16 + q * 4;
#pragma unroll
            for (int r = 0; r < 4; ++r) {
                const size_t rowi = (size_t)(n * CC + c + r) * HH;
                const float t1v = t1[rowi + h];
                const float xv = x[(rowi + h) * WW + w];
                const float xr = x[(rowi + hprev) * WW + w];
                out[(rowi + h) * WW + w] = t1v - (t9v * xr + xv * acc[ct][st][r]);
            }
        }
    }
}

extern "C" void kernel_launch(void* const* d_in, const int* in_sizes, int n_in,
                              void* d_out, int out_size, void* d_ws, size_t ws_size,
                              hipStream_t stream) {
    const float* x  = (const float*)d_in[0];
    const float* w6 = (const float*)d_in[1];
    const float* w7 = (const float*)d_in[2];
    float* out = (float*)d_out;
    char* ws = (char*)d_ws;
    u16*   xp2 = (u16*)(ws + XP2_OFF);
    u16*   wt3 = (u16*)(ws + WT3_OFF);
    float* t1  = (float*)(ws + T1_OFF);
    float* t9  = (float*)(ws + T9_OFF);

    zero_xp2<<<dim3(2048), dim3(256), 0, stream>>>(xp2, XP2_BYTES / 16);
    pack_x<<<dim3(NN * HH), dim3(256), 0, stream>>>(x, xp2);
    pack_w<<<dim3(6400), dim3(256), 0, stream>>>(w7, wt3);
    t169_kernel<<<dim3(NN * HH), dim3(256), 0, stream>>>(x, w6, t1, t9);
    conv_main<<<dim3(1568), dim3(256), 0, stream>>>((const char*)xp2, (const char*)wt3,
                                                    x, t1, t9, out);
}